// Round 8
// baseline (447.548 us; speedup 1.0000x reference)
//
#include <hip/hip_runtime.h>
#include <cstdint>

#define D 128
#define P 8
#define L 3

#define CHUNK 32      // edges per staged chunk
#define NBUF 3        // staging buffers (tri-buffer: no reuse race window)
#define MAXE 256      // per-wave epk window (1 KB = one global_load_lds(16))

typedef __attribute__((ext_vector_type(8))) _Float16 f16x8;
typedef __attribute__((ext_vector_type(4))) float    f32x4;
typedef __attribute__((ext_vector_type(2))) float    f32x2;

#if __has_builtin(__builtin_amdgcn_cvt_pk_f32_fp8) && __has_builtin(__builtin_amdgcn_cvt_pk_fp8_f32)
#define HAVE_FP8_CVT 1
#else
#define HAVE_FP8_CVT 0
#endif

// ---- direct global->LDS DMA (no VGPR cost per in-flight load) ----
typedef const __attribute__((address_space(1))) void* gas_t;
typedef __attribute__((address_space(3))) void*       las_t;
static __device__ __forceinline__ void glds16(const void* g, void* l) {
    __builtin_amdgcn_global_load_lds((gas_t)g, (las_t)l, 16, 0, 0);
}
static __device__ __forceinline__ void glds4(const void* g, void* l) {
    __builtin_amdgcn_global_load_lds((gas_t)g, (las_t)l, 4, 0, 0);
}
static __device__ __forceinline__ void waitvm0() {
    asm volatile("s_waitcnt vmcnt(0)" ::: "memory");
}
static __device__ __forceinline__ void waitvm5() {
    asm volatile("s_waitcnt vmcnt(5)" ::: "memory");   // allow newest chunk's 5 DMAs outstanding
}

// ---- fp8 e4m3fn -> f32 pair (OCP, gfx950). HI selects bytes 2,3 (imm operand).
template<bool HI>
static __device__ __forceinline__ f32x2 fp8_pair(uint32_t u) {
#if HAVE_FP8_CVT
    return __builtin_amdgcn_cvt_pk_f32_fp8((int)u, HI);
#else
    uint32_t w = HI ? (u >> 16) : u;
    f32x2 r;
#pragma unroll
    for (int i = 0; i < 2; i++) {
        uint32_t b = (w >> (8 * i)) & 0xffu;
        uint32_t mag = b & 0x7fu;
        uint16_t h = (uint16_t)(((b & 0x80u) << 8) | ((mag >= 8u) ? ((mag << 7) + 0x2000u) : 0u));
        union { uint16_t q; _Float16 hf; } c; c.q = h;
        r[i] = (float)c.hf;
    }
    return r;
#endif
}

static __device__ __forceinline__ uint32_t f32_to_fp8(float v) {
#if HAVE_FP8_CVT
    return (uint32_t)__builtin_amdgcn_cvt_pk_fp8_f32(v, v, 0, false) & 0xffu;
#else
    union { _Float16 hf; uint16_t q; } c; c.hf = (_Float16)v;
    uint32_t s = ((uint32_t)c.q >> 8) & 0x80u;
    int t = (int)(c.q & 0x7fff) - 0x2000;
    if (t < 0) return s;
    int r = (t + 63 + ((t >> 7) & 1)) >> 7;
    if (r > 0x7e) r = 0x7e;
    return s | (uint32_t)r;
#endif
}

// epk[i] = (col << 15) | f16bits(val); row_ptr via adjacent-difference.
__global__ void prep_edges(const int* __restrict__ er, const int* __restrict__ col,
                           const float* __restrict__ vals,
                           int* __restrict__ rp, uint32_t* __restrict__ epk,
                           int n, int e) {
    int i = blockIdx.x * blockDim.x + threadIdx.x;
    if (i >= e) return;
    union { _Float16 h; uint16_t u; } v;
    v.h = (_Float16)vals[i];
    epk[i] = ((uint32_t)col[i] << 15) | (uint32_t)(v.u & 0x7FFFu);
    int cur = er[i];
    if (i == 0) {
        for (int r = 0; r <= cur; r++) rp[r] = 0;
    } else {
        int prev = er[i - 1];
        for (int r = prev + 1; r <= cur; r++) rp[r] = i;
    }
    if (i == e - 1) {
        for (int r = cur + 1; r <= n; r++) rp[r] = e;
    }
}

// ww = softmax-contracted weights, fp16, MFMA B-frag layout.
__global__ void build_ww(const float* __restrict__ sp, const float* __restrict__ lw,
                         _Float16* __restrict__ wwB) {
    int idx = blockIdx.x * blockDim.x + threadIdx.x;
    if (idx >= L * D * D) return;
    int l = idx / (D * D);
    int rem = idx - l * D * D;
    int o = rem / D;
    int i = rem - o * D;
    float wv[P];
    float m = -1e30f;
#pragma unroll
    for (int p = 0; p < P; p++) { wv[p] = lw[l * P + p]; m = fmaxf(m, wv[p]); }
    float s = 0.f;
#pragma unroll
    for (int p = 0; p < P; p++) { wv[p] = __expf(wv[p] - m); s += wv[p]; }
    float inv = 1.0f / s;
    const float* spp = sp + ((size_t)(l * D + o) * D + i) * P;
    float acc = 0.f;
#pragma unroll
    for (int p = 0; p < P; p++) acc += spp[p] * wv[p];
    int kt = i >> 5, kp = i & 31;
    wwB[(((l * 4 + kt) * D + o) << 5) + kp] = (_Float16)(acc * inv);
}

// MFMA on 32x128 staged tile; quantize output to fp8 + per-row scale.
static __device__ __forceinline__ void mfma_store32_q8(const _Float16 (*s_h)[136],
                                                       const _Float16* __restrict__ wwB_l,
                                                       uint8_t* __restrict__ y8,
                                                       float* __restrict__ scl,
                                                       unsigned* srow,
                                                       int row0, int n, int tid) {
    const int w = tid >> 6, lane = tid & 63;
    const int quad = lane >> 4, l16 = lane & 15;
    f32x4 acc[2][2] = {};
#pragma unroll
    for (int kt = 0; kt < 4; kt++) {
        f16x8 af0 = *(const f16x8*)&s_h[l16][kt * 32 + quad * 8];
        f16x8 af1 = *(const f16x8*)&s_h[16 + l16][kt * 32 + quad * 8];
#pragma unroll
        for (int c = 0; c < 2; c++) {
            const int ct = w * 2 + c;
            f16x8 bf = *(const f16x8*)&wwB_l[((kt * D + ct * 16 + l16) << 5) + quad * 8];
            acc[0][c] = __builtin_amdgcn_mfma_f32_16x16x32_f16(af0, bf, acc[0][c], 0, 0, 0);
            acc[1][c] = __builtin_amdgcn_mfma_f32_16x16x32_f16(af1, bf, acc[1][c], 0, 0, 0);
        }
    }
#pragma unroll
    for (int rt = 0; rt < 2; rt++) {
#pragma unroll
        for (int rg = 0; rg < 4; rg++) {
            float m = fmaxf(fabsf(acc[rt][0][rg]), fabsf(acc[rt][1][rg]));
#pragma unroll
            for (int d = 1; d < 16; d <<= 1) m = fmaxf(m, __shfl_xor(m, d));
            if (l16 == 0) atomicMax(&srow[rt * 16 + quad * 4 + rg], __float_as_uint(m));
        }
    }
    __syncthreads();
#pragma unroll
    for (int rt = 0; rt < 2; rt++) {
#pragma unroll
        for (int rg = 0; rg < 4; rg++) {
            const int rr = rt * 16 + quad * 4 + rg;
            const int row = row0 + rr;
            float rmax = fmaxf(__uint_as_float(srow[rr]), 1e-20f);
            float qs = 448.f / rmax;
            if (row < n) {
#pragma unroll
                for (int c = 0; c < 2; c++) {
                    const int ct = w * 2 + c;
                    float v = acc[rt][c][rg] * qs;
                    v = fminf(fmaxf(v, -448.f), 448.f);
                    y8[row * D + ct * 16 + l16] = (uint8_t)f32_to_fp8(v);
                }
                if (w == 0 && l16 == 0) scl[row] = rmax * (1.f / 448.f);
            }
        }
    }
}

// Y1 = cast_f16(x) * W0, quantized. 32-row tiles. (unchanged from r7)
__global__ __launch_bounds__(256, 8)
void gemm_x32(const float* __restrict__ x, const _Float16* __restrict__ wwB_l,
              uint8_t* __restrict__ y8, float* __restrict__ scl, int n) {
    __shared__ _Float16 s_h[32][136];
    __shared__ unsigned srow[32];
    const int tid = threadIdx.x;
    const int row0 = blockIdx.x * 32;
    const int c8 = (tid & 15) * 8;
    if (tid < 32) srow[tid] = 0;
    {
        int r = tid >> 4;
#pragma unroll
        for (int h2 = 0; h2 < 2; h2++) {
            int rr = r + h2 * 16;
            int row = row0 + rr;
            float4 v0 = {}, v1 = {};
            if (row < n) {
                v0 = *(const float4*)&x[row * D + c8];
                v1 = *(const float4*)&x[row * D + c8 + 4];
            }
            f16x8 h;
            h[0] = (_Float16)v0.x; h[1] = (_Float16)v0.y;
            h[2] = (_Float16)v0.z; h[3] = (_Float16)v0.w;
            h[4] = (_Float16)v1.x; h[5] = (_Float16)v1.y;
            h[6] = (_Float16)v1.z; h[7] = (_Float16)v1.w;
            *(f16x8*)&s_h[rr][c8] = h;
        }
    }
    __syncthreads();
    mfma_store32_q8(s_h, wwB_l, y8, scl, srow, row0, n, tid);
}

// ================= wave-private DMA-staged gather core =================
// Wave owns 8 rows (subgroup sg = lane>>3 owns one). Contiguous edge window
// [wb, wb+MAXE) staged: epk via 1 DMA; then CHUNK-edge row+scl DMAs, counted
// vmcnt pipeline 2 deep. No barriers, no VGPRs for in-flight data.
// LDS layout per wave: s_stage[NBUF][CHUNK*128] + s_sclb[NBUF][CHUNK*2] + s_epk[MAXE].
// XOR source-swizzle (key = slot&7 == stage-sgid) kills ds_read_b128 bank conflicts.
static __device__ __forceinline__ void gather_rows_staged(
        float (&a)[16],
        const uint8_t* __restrict__ y8, const float* __restrict__ scl,
        const int* __restrict__ rp, const uint32_t* __restrict__ epk,
        uint8_t (*s_stage)[CHUNK * 128], float (*s_sclb)[CHUNK * 2],
        uint32_t* s_epk, int row0w, int n, int lane) {
    const int sgid = lane >> 3;
    const int l8 = lane & 7;
    const int r = row0w + sgid;
    int e0r = 0, e1r = 0;
    if (r < n) { e0r = rp[r]; e1r = rp[r + 1]; }
    const int rlo = row0w < n ? row0w : n;
    int rhi = row0w + 8; rhi = rhi < n ? rhi : n;
    const int e0w = rp[rlo];
    const int e1w = rp[rhi < rlo ? rlo : rhi];

    for (int wb = e0w; wb < e1w; wb += MAXE) {
        const int wcnt = (e1w - wb) < MAXE ? (e1w - wb) : MAXE;
        const int nch = (wcnt + CHUNK - 1) / CHUNK;
        // stage epk window: lane covers 4 consecutive epk (16 B)
        glds16(epk + wb + lane * 4, s_epk);
        waitvm0();                         // epk ready (drains prev window leftovers too)

        auto stage_chunk = [&](int cc) {
            const int bi = cc % NBUF;
            const int erel0 = cc * CHUNK;
#pragma unroll
            for (int k = 0; k < 4; k++) {
                int er = erel0 + k * 8 + sgid;
                er = er < wcnt ? er : wcnt - 1;          // clamp: dummy re-fetch, unread
                uint32_t m = s_epk[er];
                // source-swizzled 16B: lane l8 fetches row bytes (l8^sgid)*16,
                // lands at LDS +lane*16; read side applies the same XOR.
                const uint8_t* gp = y8 + (size_t)(m >> 15) * D + ((l8 ^ sgid) << 4);
                glds16(gp, (void*)&s_stage[bi][k * 1024]);
            }
            {   // scl DMA: lane covers edge (lane>>1); 2 copies per edge in LDS
                int er = erel0 + (lane >> 1);
                er = er < wcnt ? er : wcnt - 1;
                uint32_t m = s_epk[er];
                glds4(scl + (m >> 15), (void*)&s_sclb[bi][0]);
            }
        };

        stage_chunk(0);
        stage_chunk(1);
        for (int c = 0; c < nch; c++) {
            waitvm5();                     // chunk c landed; c+1 may stay in flight
            const int bi = c % NBUF;
            const int cb = wb + c * CHUNK;
            int s0 = e0r > cb ? e0r : cb;
            int t0 = e1r < cb + CHUNK ? e1r : cb + CHUNK;
            for (int e = s0; e < t0; e++) {
                const int slot = e - cb;
                const int sw = (l8 ^ (slot & 7)) << 4;   // inverse of source swizzle
                uint4 g = *(const uint4*)&s_stage[bi][slot * 128 + sw];
                uint32_t mv = s_epk[e - wb];
                union { uint16_t u; _Float16 h; } vv; vv.u = (uint16_t)(mv & 0x7FFFu);
                float coef = s_sclb[bi][slot * 2] * (float)vv.h;
                f32x2 p;
                p = fp8_pair<false>(g.x); a[ 0] += coef * p[0]; a[ 1] += coef * p[1];
                p = fp8_pair<true >(g.x); a[ 2] += coef * p[0]; a[ 3] += coef * p[1];
                p = fp8_pair<false>(g.y); a[ 4] += coef * p[0]; a[ 5] += coef * p[1];
                p = fp8_pair<true >(g.y); a[ 6] += coef * p[0]; a[ 7] += coef * p[1];
                p = fp8_pair<false>(g.z); a[ 8] += coef * p[0]; a[ 9] += coef * p[1];
                p = fp8_pair<true >(g.z); a[10] += coef * p[0]; a[11] += coef * p[1];
                p = fp8_pair<false>(g.w); a[12] += coef * p[0]; a[13] += coef * p[1];
                p = fp8_pair<true >(g.w); a[14] += coef * p[0]; a[15] += coef * p[1];
            }
            stage_chunk(c + 2);            // unconditional: clamped dummies keep vmcnt bookkeeping fixed
        }
    }
}

// Fused layer: Y_next = q8( relu(adj * deq(Y_prev)) * W ). 32-row tiles.
__global__ __launch_bounds__(256)
__attribute__((amdgpu_waves_per_eu(2, 2)))
void fused_layer(const uint8_t* __restrict__ yprev, const float* __restrict__ sprev,
                 const int* __restrict__ rp, const uint32_t* __restrict__ epk,
                 const _Float16* __restrict__ wwB_l,
                 uint8_t* __restrict__ ynext, float* __restrict__ snext, int n) {
    __shared__ __align__(16) uint8_t  s_stage[4][NBUF][CHUNK * 128];  // 48 KB
    __shared__ __align__(16) float    s_sclb [4][NBUF][CHUNK * 2];    // 3 KB
    __shared__ __align__(16) uint32_t s_epk  [4][MAXE];               // 4 KB
    __shared__ _Float16 s_h[32][136];                                 // 8.5 KB
    __shared__ unsigned srow[32];
    const int tid = threadIdx.x;
    const int lane = tid & 63;
    const int w = tid >> 6;
    const int row0 = blockIdx.x * 32;
    if (tid < 32) srow[tid] = 0;

    float a[16] = {};
    gather_rows_staged(a, yprev, sprev, rp, epk,
                       s_stage[w], s_sclb[w], s_epk[w], row0 + w * 8, n, lane);
    {
        const int sg = tid >> 3;           // 0..31 = w*8 + sgid: this thread's row slot
        const int c16 = (lane & 7) * 16;
        f16x8 o0, o1;
#pragma unroll
        for (int k = 0; k < 8; k++) {
            o0[k] = (_Float16)fmaxf(a[k], 0.f);
            o1[k] = (_Float16)fmaxf(a[8 + k], 0.f);
        }
        *(f16x8*)&s_h[sg][c16]     = o0;
        *(f16x8*)&s_h[sg][c16 + 8] = o1;
    }
    __syncthreads();
    mfma_store32_q8(s_h, wwB_l, ynext, snext, srow, row0, n, tid);
}

// Final: out = adj * deq(Y3), fp32 out.
__global__ __launch_bounds__(256)
__attribute__((amdgpu_waves_per_eu(2, 2)))
void spmm_f32(const uint8_t* __restrict__ y8, const float* __restrict__ sprev,
              const int* __restrict__ rp, const uint32_t* __restrict__ epk,
              float* __restrict__ out, int n) {
    __shared__ __align__(16) uint8_t  s_stage[4][NBUF][CHUNK * 128];
    __shared__ __align__(16) float    s_sclb [4][NBUF][CHUNK * 2];
    __shared__ __align__(16) uint32_t s_epk  [4][MAXE];
    const int tid = threadIdx.x;
    const int lane = tid & 63;
    const int w = tid >> 6;
    const int row0 = blockIdx.x * 32;

    float a[16] = {};
    gather_rows_staged(a, y8, sprev, rp, epk,
                       s_stage[w], s_sclb[w], s_epk[w], row0 + w * 8, n, lane);
    const int r = row0 + (tid >> 3);
    if (r >= n) return;
    float* o = &out[(size_t)r * D + (lane & 7) * 16];
    *(float4*)&o[ 0] = make_float4(a[ 0], a[ 1], a[ 2], a[ 3]);
    *(float4*)&o[ 4] = make_float4(a[ 4], a[ 5], a[ 6], a[ 7]);
    *(float4*)&o[ 8] = make_float4(a[ 8], a[ 9], a[10], a[11]);
    *(float4*)&o[12] = make_float4(a[12], a[13], a[14], a[15]);
}

extern "C" void kernel_launch(void* const* d_in, const int* in_sizes, int n_in,
                              void* d_out, int out_size, void* d_ws, size_t ws_size,
                              hipStream_t stream) {
    const int*   edge_row  = (const int*)d_in[0];
    const int*   edge_col  = (const int*)d_in[1];
    const float* edge_vals = (const float*)d_in[2];
    const float* x         = (const float*)d_in[3];
    const float* sp        = (const float*)d_in[4];
    const float* lw        = (const float*)d_in[5];
    float* out = (float*)d_out;

    const int E_ = in_sizes[0];
    const int N_ = in_sizes[3] / D;

    // Workspace: row_ptr | epk | wwB | y8A | y8B | scA | scB
    char* ws = (char*)d_ws;
    int* row_ptr = (int*)ws;
    size_t off = (((size_t)(N_ + 1) * sizeof(int)) + 255) & ~(size_t)255;
    uint32_t* epk = (uint32_t*)(ws + off);
    off += (size_t)E_ * sizeof(uint32_t);
    off = (off + 255) & ~(size_t)255;
    _Float16* wwB = (_Float16*)(ws + off);
    off += (size_t)L * 4 * D * 32 * sizeof(_Float16);
    off = (off + 255) & ~(size_t)255;
    uint8_t* y8A = (uint8_t*)(ws + off);
    off += (size_t)N_ * D;
    uint8_t* y8B = (uint8_t*)(ws + off);
    off += (size_t)N_ * D;
    off = (off + 255) & ~(size_t)255;
    float* scA = (float*)(ws + off);
    off += (size_t)N_ * sizeof(float);
    float* scB = (float*)(ws + off);

    prep_edges<<<(E_ + 255) / 256, 256, 0, stream>>>(edge_row, edge_col, edge_vals,
                                                     row_ptr, epk, N_, E_);
    build_ww<<<(L * D * D + 255) / 256, 256, 0, stream>>>(sp, lw, wwB);

    const int sblk = (N_ + 31) / 32;
    const int WWL = 4 * D * 32;

    gemm_x32<<<sblk, 256, 0, stream>>>(x, wwB, y8A, scA, N_);
    fused_layer<<<sblk, 256, 0, stream>>>(y8A, scA, row_ptr, epk, wwB + WWL,     y8B, scB, N_);
    fused_layer<<<sblk, 256, 0, stream>>>(y8B, scB, row_ptr, epk, wwB + 2 * WWL, y8A, scA, N_);
    spmm_f32<<<sblk, 256, 0, stream>>>(y8A, scA, row_ptr, epk, out, N_);
}

// Round 9
// 270.868 us; speedup vs baseline: 1.6523x; 1.6523x over previous
//
#include <hip/hip_runtime.h>
#include <cstdint>

#define D 128
#define P 8
#define L 3

typedef __attribute__((ext_vector_type(8))) _Float16 f16x8;
typedef __attribute__((ext_vector_type(4))) float    f32x4;
typedef __attribute__((ext_vector_type(2))) float    f32x2;
typedef __attribute__((ext_vector_type(4))) uint32_t u32x4;
typedef u32x4 __attribute__((aligned(4))) u32x4_u;   // 4B-aligned vector load (e arbitrary)

#if __has_builtin(__builtin_amdgcn_cvt_pk_f32_fp8) && __has_builtin(__builtin_amdgcn_cvt_pk_fp8_f32)
#define HAVE_FP8_CVT 1
#else
#define HAVE_FP8_CVT 0
#endif

// ---- fp8 e4m3fn -> f32 pair (OCP, gfx950). HI selects bytes 2,3 (imm operand).
template<bool HI>
static __device__ __forceinline__ f32x2 fp8_pair(uint32_t u) {
#if HAVE_FP8_CVT
    return __builtin_amdgcn_cvt_pk_f32_fp8((int)u, HI);
#else
    uint32_t w = HI ? (u >> 16) : u;
    f32x2 r;
#pragma unroll
    for (int i = 0; i < 2; i++) {
        uint32_t b = (w >> (8 * i)) & 0xffu;
        uint32_t mag = b & 0x7fu;
        uint16_t h = (uint16_t)(((b & 0x80u) << 8) | ((mag >= 8u) ? ((mag << 7) + 0x2000u) : 0u));
        union { uint16_t q; _Float16 hf; } c; c.q = h;
        r[i] = (float)c.hf;
    }
    return r;
#endif
}

static __device__ __forceinline__ uint32_t f32_to_fp8(float v) {
#if HAVE_FP8_CVT
    return (uint32_t)__builtin_amdgcn_cvt_pk_fp8_f32(v, v, 0, false) & 0xffu;
#else
    union { _Float16 hf; uint16_t q; } c; c.hf = (_Float16)v;
    uint32_t s = ((uint32_t)c.q >> 8) & 0x80u;
    int t = (int)(c.q & 0x7fff) - 0x2000;
    if (t < 0) return s;
    int r = (t + 63 + ((t >> 7) & 1)) >> 7;
    if (r > 0x7e) r = 0x7e;
    return s | (uint32_t)r;
#endif
}

// Merged prep: epk pack + row_ptr adjacent-diff + ww softmax-contraction.
__global__ void prep_all(const int* __restrict__ er, const int* __restrict__ col,
                         const float* __restrict__ vals,
                         const float* __restrict__ sp, const float* __restrict__ lw,
                         int* __restrict__ rp, uint32_t* __restrict__ epk,
                         _Float16* __restrict__ wwB, int n, int e) {
    int i = blockIdx.x * blockDim.x + threadIdx.x;
    if (i < e) {
        union { _Float16 h; uint16_t u; } v;
        v.h = (_Float16)vals[i];
        epk[i] = ((uint32_t)col[i] << 15) | (uint32_t)(v.u & 0x7FFFu);
        int cur = er[i];
        if (i == 0) {
            for (int r = 0; r <= cur; r++) rp[r] = 0;
        } else {
            int prev = er[i - 1];
            for (int r = prev + 1; r <= cur; r++) rp[r] = i;
        }
        if (i == e - 1) {
            for (int r = cur + 1; r <= n; r++) rp[r] = e;
        }
    }
    if (i < L * D * D) {
        int l = i / (D * D);
        int rem = i - l * D * D;
        int o = rem / D;
        int ii = rem - o * D;
        float wv[P];
        float m = -1e30f;
#pragma unroll
        for (int p = 0; p < P; p++) { wv[p] = lw[l * P + p]; m = fmaxf(m, wv[p]); }
        float s = 0.f;
#pragma unroll
        for (int p = 0; p < P; p++) { wv[p] = __expf(wv[p] - m); s += wv[p]; }
        float inv = 1.0f / s;
        const float* spp = sp + ((size_t)(l * D + o) * D + ii) * P;
        float acc = 0.f;
#pragma unroll
        for (int p = 0; p < P; p++) acc += spp[p] * wv[p];
        int kt = ii >> 5, kp = ii & 31;
        wwB[(((l * 4 + kt) * D + o) << 5) + kp] = (_Float16)(acc * inv);
    }
}

// MFMA on 16x128 tile, TWO waves: each wave does 4 col-tiles. fp8+scale output.
// srow: LDS[16] pre-zeroed by caller before its __syncthreads().
static __device__ __forceinline__ void mfma2w_q8(const _Float16 (*s_h)[136],
                                                 const _Float16* __restrict__ wwB_l,
                                                 uint8_t* __restrict__ y8,
                                                 float* __restrict__ scl,
                                                 unsigned* srow,
                                                 int row0, int n, int tid) {
    const int w = tid >> 6, lane = tid & 63;     // w in {0,1}
    const int quad = lane >> 4, l16 = lane & 15;
    f32x4 acc[4] = {};
#pragma unroll
    for (int kt = 0; kt < 4; kt++) {
        f16x8 af = *(const f16x8*)&s_h[l16][kt * 32 + quad * 8];
#pragma unroll
        for (int c = 0; c < 4; c++) {
            const int ct = w * 4 + c;
            f16x8 bf = *(const f16x8*)&wwB_l[((kt * D + ct * 16 + l16) << 5) + quad * 8];
            acc[c] = __builtin_amdgcn_mfma_f32_16x16x32_f16(af, bf, acc[c], 0, 0, 0);
        }
    }
    // C/D layout: col = lane&15, row = quad*4 + reg (m89-verified).
#pragma unroll
    for (int rg = 0; rg < 4; rg++) {
        float m = fmaxf(fmaxf(fabsf(acc[0][rg]), fabsf(acc[1][rg])),
                        fmaxf(fabsf(acc[2][rg]), fabsf(acc[3][rg])));
#pragma unroll
        for (int d = 1; d < 16; d <<= 1) m = fmaxf(m, __shfl_xor(m, d));
        if (l16 == 0) atomicMax(&srow[quad * 4 + rg], __float_as_uint(m));
    }
    __syncthreads();
#pragma unroll
    for (int rg = 0; rg < 4; rg++) {
        const int rr = quad * 4 + rg;
        const int row = row0 + rr;
        float rmax = fmaxf(__uint_as_float(srow[rr]), 1e-20f);
        float qs = 448.f / rmax;
        if (row < n) {
#pragma unroll
            for (int c = 0; c < 4; c++) {
                const int ct = w * 4 + c;
                float v = acc[c][rg] * qs;
                v = fminf(fmaxf(v, -448.f), 448.f);
                y8[row * D + ct * 16 + l16] = (uint8_t)f32_to_fp8(v);
            }
            if (w == 0 && l16 == 0) scl[row] = rmax * (1.f / 448.f);
        }
    }
}

// Y1 = cast_f16(x) * W0, quantized. 16-row tiles, 128 threads (each sg 2 rows).
__global__ __launch_bounds__(128, 8)
void gemm_x32(const float* __restrict__ x, const _Float16* __restrict__ wwB_l,
              uint8_t* __restrict__ y8, float* __restrict__ scl, int n) {
    __shared__ _Float16 s_h[16][136];
    __shared__ unsigned srow[16];
    const int tid = threadIdx.x;
    const int row0 = blockIdx.x * 16;
    const int sg = tid >> 4;          // 0..7
    const int c8 = (tid & 15) * 8;
    if (tid < 16) srow[tid] = 0;
#pragma unroll
    for (int h2 = 0; h2 < 2; h2++) {
        int rr = sg + h2 * 8;
        int row = row0 + rr;
        float4 v0 = {}, v1 = {};
        if (row < n) {
            v0 = *(const float4*)&x[row * D + c8];
            v1 = *(const float4*)&x[row * D + c8 + 4];
        }
        f16x8 h;
        h[0] = (_Float16)v0.x; h[1] = (_Float16)v0.y;
        h[2] = (_Float16)v0.z; h[3] = (_Float16)v0.w;
        h[4] = (_Float16)v1.x; h[5] = (_Float16)v1.y;
        h[6] = (_Float16)v1.z; h[7] = (_Float16)v1.w;
        *(f16x8*)&s_h[rr][c8] = h;
    }
    __syncthreads();
    mfma2w_q8(s_h, wwB_l, y8, scl, srow, row0, n, tid);
}

// ------------- r4 gather core + one-chunk-ahead epk prefetch -------------
// 16 lanes per row, uint2 (8B) gathers, 4 concurrent rows per wave.
template<int NB>
static __device__ __forceinline__ void gather_chunk8(float (&a)[8],
                                                     const uint8_t* __restrict__ y8,
                                                     const uint32_t* __restrict__ epk,
                                                     const float* __restrict__ scl,
                                                     int e, int c8) {
    uint32_t m[NB];
#pragma unroll
    for (int j = 0; j < NB; j++) m[j] = epk[e + j];
    uint2 g[NB]; float sc[NB];
#pragma unroll
    for (int j = 0; j < NB; j++) {
        uint32_t row = m[j] >> 15;
        g[j]  = *(const uint2*)&y8[row * (uint32_t)D + (uint32_t)c8];
        sc[j] = scl[row];
    }
#pragma unroll
    for (int j = 0; j < NB; j++) {
        union { uint16_t u; _Float16 h; } vv; vv.u = (uint16_t)(m[j] & 0x7FFFu);
        float vf = (float)vv.h * sc[j];
        f32x2 p;
        p = fp8_pair<false>(g[j].x); a[0] += vf * p[0]; a[1] += vf * p[1];
        p = fp8_pair<true >(g[j].x); a[2] += vf * p[0]; a[3] += vf * p[1];
        p = fp8_pair<false>(g[j].y); a[4] += vf * p[0]; a[5] += vf * p[1];
        p = fp8_pair<true >(g[j].y); a[6] += vf * p[0]; a[7] += vf * p[1];
    }
}

// Pipelined full-chunk loop: epk for chunk c+1 is loaded (2 dword-aligned
// vector loads) while chunk c's gathers are in flight / FMAs run. Removes one
// serial L2-latency level from the per-chunk chain.
static __device__ __forceinline__ void gather_row8_pipe(float (&a)[8],
                                                        const uint8_t* __restrict__ y8,
                                                        const uint32_t* __restrict__ epk,
                                                        const float* __restrict__ scl,
                                                        int e, int e1, int c8) {
    const int nfull = (e1 - e) >> 3;
    u32x4 mA = {}, mB = {};
    if (nfull > 0) {
        mA = *(const u32x4_u*)&epk[e];
        mB = *(const u32x4_u*)&epk[e + 4];
    }
    for (int c = 0; c < nfull; c++) {
        uint32_t m[8] = { mA.x, mA.y, mA.z, mA.w, mB.x, mB.y, mB.z, mB.w };
        uint2 g[8]; float sc[8];
#pragma unroll
        for (int j = 0; j < 8; j++) {
            uint32_t row = m[j] >> 15;
            g[j]  = *(const uint2*)&y8[row * (uint32_t)D + (uint32_t)c8];
            sc[j] = scl[row];
        }
        if (c + 1 < nfull) {               // prefetch next chunk's meta NOW
            const int en = e + (c + 1) * 8;
            mA = *(const u32x4_u*)&epk[en];
            mB = *(const u32x4_u*)&epk[en + 4];
        }
#pragma unroll
        for (int j = 0; j < 8; j++) {
            union { uint16_t u; _Float16 h; } vv; vv.u = (uint16_t)(m[j] & 0x7FFFu);
            float vf = (float)vv.h * sc[j];
            f32x2 p;
            p = fp8_pair<false>(g[j].x); a[0] += vf * p[0]; a[1] += vf * p[1];
            p = fp8_pair<true >(g[j].x); a[2] += vf * p[0]; a[3] += vf * p[1];
            p = fp8_pair<false>(g[j].y); a[4] += vf * p[0]; a[5] += vf * p[1];
            p = fp8_pair<true >(g[j].y); a[6] += vf * p[0]; a[7] += vf * p[1];
        }
    }
    e += nfull * 8;
    if (e + 4 <= e1) { gather_chunk8<4>(a, y8, epk, scl, e, c8); e += 4; }
    for (; e < e1; e++) gather_chunk8<1>(a, y8, epk, scl, e, c8);
}

// Fused layer: Y_next = q8( relu(adj * deq(Y_prev)) * W ).  16-row tiles,
// 128 threads (2 waves): 8 subgroups x 2 rows each; 2-wave MFMA epilogue.
__global__ __launch_bounds__(128, 8)
void fused_layer(const uint8_t* __restrict__ yprev, const float* __restrict__ sprev,
                 const int* __restrict__ rp, const uint32_t* __restrict__ epk,
                 const _Float16* __restrict__ wwB_l,
                 uint8_t* __restrict__ ynext, float* __restrict__ snext, int n) {
    __shared__ _Float16 s_h[16][136];
    __shared__ unsigned srow[16];
    const int tid = threadIdx.x;
    const int row0 = blockIdx.x * 16;
    const int sg = tid >> 4;          // 0..7
    const int c8 = (tid & 15) * 8;
    if (tid < 16) srow[tid] = 0;
#pragma unroll
    for (int h2 = 0; h2 < 2; h2++) {
        const int rr = sg + h2 * 8;
        const int r = row0 + rr;
        float a[8] = {0.f, 0.f, 0.f, 0.f, 0.f, 0.f, 0.f, 0.f};
        if (r < n) gather_row8_pipe(a, yprev, epk, sprev, rp[r], rp[r + 1], c8);
        f16x8 o;
#pragma unroll
        for (int k = 0; k < 8; k++) o[k] = (_Float16)fmaxf(a[k], 0.f);
        *(f16x8*)&s_h[rr][c8] = o;
    }
    __syncthreads();
    mfma2w_q8(s_h, wwB_l, ynext, snext, srow, row0, n, tid);
}

// Final: out = adj * deq(Y3), fp32 out. 128 threads, 8 rows/block.
__global__ __launch_bounds__(128, 8)
void spmm_f32(const uint8_t* __restrict__ y8, const float* __restrict__ sprev,
              const int* __restrict__ rp, const uint32_t* __restrict__ epk,
              float* __restrict__ out, int n) {
    const int tid = threadIdx.x;
    const int r = blockIdx.x * 8 + (tid >> 4);
    const int c8 = (tid & 15) * 8;
    if (r >= n) return;
    float a[8] = {0.f, 0.f, 0.f, 0.f, 0.f, 0.f, 0.f, 0.f};
    gather_row8_pipe(a, y8, epk, sprev, rp[r], rp[r + 1], c8);
    *(float4*)&out[(size_t)r * D + c8]     = make_float4(a[0], a[1], a[2], a[3]);
    *(float4*)&out[(size_t)r * D + c8 + 4] = make_float4(a[4], a[5], a[6], a[7]);
}

extern "C" void kernel_launch(void* const* d_in, const int* in_sizes, int n_in,
                              void* d_out, int out_size, void* d_ws, size_t ws_size,
                              hipStream_t stream) {
    const int*   edge_row  = (const int*)d_in[0];
    const int*   edge_col  = (const int*)d_in[1];
    const float* edge_vals = (const float*)d_in[2];
    const float* x         = (const float*)d_in[3];
    const float* sp        = (const float*)d_in[4];
    const float* lw        = (const float*)d_in[5];
    float* out = (float*)d_out;

    const int E_ = in_sizes[0];
    const int N_ = in_sizes[3] / D;

    // Workspace: row_ptr | epk | wwB | y8A | y8B | scA | scB   (~33 MB)
    char* ws = (char*)d_ws;
    int* row_ptr = (int*)ws;
    size_t off = (((size_t)(N_ + 1) * sizeof(int)) + 255) & ~(size_t)255;
    uint32_t* epk = (uint32_t*)(ws + off);
    off += (size_t)E_ * sizeof(uint32_t);
    off = (off + 255) & ~(size_t)255;
    _Float16* wwB = (_Float16*)(ws + off);
    off += (size_t)L * 4 * D * 32 * sizeof(_Float16);
    off = (off + 255) & ~(size_t)255;
    uint8_t* y8A = (uint8_t*)(ws + off);
    off += (size_t)N_ * D;
    uint8_t* y8B = (uint8_t*)(ws + off);
    off += (size_t)N_ * D;
    off = (off + 255) & ~(size_t)255;
    float* scA = (float*)(ws + off);
    off += (size_t)N_ * sizeof(float);
    float* scB = (float*)(ws + off);

    const int pgrid = (E_ > L * D * D ? E_ : L * D * D);
    prep_all<<<(pgrid + 255) / 256, 256, 0, stream>>>(edge_row, edge_col, edge_vals,
                                                      sp, lw, row_ptr, epk, wwB, N_, E_);

    const int sblk = (N_ + 15) / 16;
    const int WWL = 4 * D * 32;   // per-layer wwB stride

    // Y1 = x*W0 ; Y2 = relu(adj*Y1)*W1 ; Y3 = relu(adj*Y2)*W2 ; out = adj*Y3
    gemm_x32<<<sblk, 128, 0, stream>>>(x, wwB, y8A, scA, N_);
    fused_layer<<<sblk, 128, 0, stream>>>(y8A, scA, row_ptr, epk, wwB + WWL,     y8B, scB, N_);
    fused_layer<<<sblk, 128, 0, stream>>>(y8B, scB, row_ptr, epk, wwB + 2 * WWL, y8A, scA, N_);
    spmm_f32<<<(N_ + 7) / 8, 128, 0, stream>>>(y8A, scA, row_ptr, epk, out, N_);
}